// Round 4
// baseline (168.879 us; speedup 1.0000x reference)
//
#include <hip/hip_runtime.h>
#include <math.h>

typedef unsigned long long ull;

// Problem constants (from setup_inputs): B=64, G=4999, P=50
constexpr int Bc = 64;
constexpr int Gc = 4999;
constexpr int Pc = 50;

constexpr int RUN  = 1024;           // elements per sorted run
constexpr int NRUN = 5;              // runs per row (5*1024 = 5120 >= G)
constexpr ull PADKEY = 0xFFFFFFFFFFFFFFFFull;
constexpr int LPW = 79;              // ceil(G/64) elements per lane in es
constexpr int WS_EPT = 16;           // elements per lane in wave_sort

__device__ __forceinline__ ull shfl_xor64(ull v, int lm) {
    int lo = __shfl_xor((int)(unsigned)(v & 0xFFFFFFFFull), lm, 64);
    int hi = __shfl_xor((int)(unsigned)(v >> 32), lm, 64);
    return ((ull)(unsigned)hi << 32) | (unsigned)lo;
}

// ---------------------------------------------------------------------------
// Kernel 1: one WAVE sorts one 1024-element run entirely in registers +
// wave shuffles. key = (~m)<<32 | idx (unique): ascending u64 == descending
// value, stable by index. j>=16 stages via shfl_xor (partner lane^(j/16),
// always intra-wave), j<=8 stages in-register. No LDS, no barriers.
// Blocks 0..19 additionally pack pathway bits (consumed by next kernel).
// ---------------------------------------------------------------------------
__global__ __launch_bounds__(64) void wave_sort(
    const float* __restrict__ expr, const float* __restrict__ pathway,
    ull* __restrict__ runs, ull* __restrict__ pbits, int P, int G)
{
    const int flat = blockIdx.x;            // 0 .. B*NRUN-1
    const int b = flat / NRUN, r = flat % NRUN;
    const int lane = threadIdx.x;           // 0..63
    const int base = lane * WS_EPT;
    const float* row = expr + (size_t)b * G;

    ull v[WS_EPT];
#pragma unroll
    for (int o = 0; o < WS_EPT; ++o) {
        int i = r * RUN + base + o;
        if (i < G) {
            unsigned u = __float_as_uint(row[i]);
            unsigned m = (u >> 31) ? ~u : (u | 0x80000000u);  // monotone map
            v[o] = ((ull)(~m) << 32) | (unsigned)i;
        } else {
            v[o] = PADKEY;
        }
    }

#pragma unroll
    for (int kk = 2; kk <= RUN; kk <<= 1) {
        // shuffle stages: j = kk/2 .. 16  (partner = lane ^ (j/16), same wave)
#pragma unroll
        for (int j = kk >> 1; j >= WS_EPT; j >>= 1) {
            const int lm = j / WS_EPT;
            const bool takeMin = (((lane & lm) == 0) == ((base & kk) == 0));
#pragma unroll
            for (int o = 0; o < WS_EPT; ++o) {
                ull c = shfl_xor64(v[o], lm);
                ull mn = (v[o] < c) ? v[o] : c;
                ull mx = (v[o] < c) ? c : v[o];
                v[o] = takeMin ? mn : mx;
            }
        }
        // register stages: j = min(kk/2, 8) .. 1
#pragma unroll
        for (int j = 8; j >= 1; j >>= 1) {
            if (j < kk) {
#pragma unroll
                for (int o = 0; o < WS_EPT; ++o) {
                    if ((o & j) == 0) {
                        bool up = (((base + o) & kk) == 0);
                        ull a = v[o], c = v[o | j];
                        if ((a > c) == up) { v[o] = c; v[o | j] = a; }
                    }
                }
            }
        }
    }

    ull* dst = runs + ((size_t)b * NRUN + r) * RUN;
#pragma unroll
    for (int o = 0; o < WS_EPT; ++o) dst[base + o] = v[o];

    // Folded pack: first 20 blocks (1280 threads) compute pbits[g].
    // Safe: pbits is only read by rank_scatter (next launch).
    if (flat < 20) {
        for (int g = flat * 64 + lane; g < G; g += 20 * 64) {
            ull m = 0;
            for (int p = 0; p < P; ++p)
                if (pathway[(size_t)p * G + g] > 0.0f) m |= (1ull << p);
            pbits[g] = m;
        }
    }
}

// ---------------------------------------------------------------------------
// Kernel 2: merge-by-rank. Block (r,b): own run's element at position q has
// global rank = q + sum over other 4 runs of countLess(key) (binary search in
// LDS). Unique keys -> bijection onto [0,G). Scatter wq (|v|^0.25 decoded
// from the key) and mask (= pbits[gene], pre-permuted into sorted order).
// 512 threads, 2 elems each: 10 waves/CU for latency hiding.
// ---------------------------------------------------------------------------
__global__ __launch_bounds__(512) void rank_scatter(
    const ull* __restrict__ runs, const ull* __restrict__ pbits,
    float* __restrict__ wqout, ull* __restrict__ maskout, int G)
{
    __shared__ ull other[4][RUN];   // 32 KB
    const int r = blockIdx.x, b = blockIdx.y, tid = threadIdx.x;
    const ull* rowruns = runs + (size_t)b * (NRUN * RUN);

    int k = 0;
    for (int rr = 0; rr < NRUN; ++rr) {
        if (rr == r) continue;
        for (int i = tid; i < RUN; i += 512) other[k][i] = rowruns[rr * RUN + i];
        ++k;
    }
    __syncthreads();

#pragma unroll
    for (int o = 0; o < 2; ++o) {
        const int q = o * 512 + tid;               // own-run rank (coalesced)
        const ull keyv = rowruns[r * RUN + q];
        if (keyv == PADKEY) continue;              // padding sorts to the end
        int rank = q;
#pragma unroll
        for (int kk2 = 0; kk2 < 4; ++kk2) {
            int pos = 0;
#pragma unroll
            for (int s = RUN; s >= 1; s >>= 1) {
                int np = pos + s;
                if (np <= RUN && other[kk2][np - 1] < keyv) pos = np;
            }
            rank += pos;                           // # elements < keyv
        }
        int idx = (int)(unsigned)(keyv & 0xFFFFFFFFu);
        unsigned m = ~((unsigned)(keyv >> 32));
        unsigned absbits = ((m >> 31) ? m : ~m) & 0x7FFFFFFFu;
        float av = __uint_as_float(absbits);
        wqout[(size_t)b * G + rank] = sqrtf(sqrtf(av));   // |v|^0.25
        maskout[(size_t)b * G + rank] = pbits[idx];
    }
}

// ---------------------------------------------------------------------------
// Kernel 3: enrichment scores. Block = 1024 threads (16 waves, 16 pathways)
// per sample b; stages wq + pre-permuted mask into LDS once (coalesced,
// contiguous — no indirection), then each wave scans from LDS.
// ---------------------------------------------------------------------------
__global__ __launch_bounds__(1024) void es_kernel(
    const float* __restrict__ wq, const ull* __restrict__ mask,
    float* __restrict__ out, int B, int P, int G)
{
    __shared__ ull   smask[Gc];   // 39992 B
    __shared__ float swq[Gc];     // 19996 B   (~60 KB total)

    const int tid = threadIdx.x;
    const int b = blockIdx.y;

    for (int i = tid; i < G; i += 1024) {
        swq[i]   = wq[(size_t)b * G + i];
        smask[i] = mask[(size_t)b * G + i];
    }
    __syncthreads();

    const int lane = tid & 63;
    const int w = tid >> 6;
    const int p = blockIdx.x * 16 + w;
    if (p >= P) return;

    const int start = lane * LPW;
    const int end = (start + LPW < G) ? (start + LPW) : G;
    const int cnt = end - start;

    // Pass A: per-chunk (sum w*hit, #hit), butterfly reduce
    double sw = 0.0;
    int sh = 0;
    for (int i = start; i < end; ++i) {
        if ((smask[i] >> p) & 1ull) { sw += (double)swq[i]; sh++; }
    }
    double swt = sw;
    int sht = sh;
#pragma unroll
    for (int off = 1; off < 64; off <<= 1) {
        swt += __shfl_xor(swt, off, 64);
        sht += __shfl_xor(sht, off, 64);
    }
    const double norm      = (swt > 0.0) ? 1.0 / swt : 1.0;
    const double inv_denom = 1.0 / fmax((double)(G - sht), 1.0);

    // Chunk sum (algebraic) + wave inclusive scan -> exclusive prefix
    double csum = sw * norm - (double)(cnt - sh) * inv_denom;
    double x = csum;
#pragma unroll
    for (int off = 1; off < 64; off <<= 1) {
        double vv = __shfl_up(x, off, 64);
        if (lane >= off) x += vv;
    }
    double running = x - csum;

    // Pass C: walk chunk, first-occurrence argmax of |running|
    double bestv = -1.0, bestr = 0.0;
    int besti = 0x7FFFFFFF;
    for (int i = start; i < end; ++i) {
        running += ((smask[i] >> p) & 1ull) ? (double)swq[i] * norm : -inv_denom;
        double a = fabs(running);
        if (a > bestv) { bestv = a; bestr = running; besti = i; }
    }
#pragma unroll
    for (int off = 1; off < 64; off <<= 1) {
        double ov  = __shfl_xor(bestv, off, 64);
        double orr = __shfl_xor(bestr, off, 64);
        int    oi  = __shfl_xor(besti, off, 64);
        if (ov > bestv || (ov == bestv && oi < besti)) {
            bestv = ov; bestr = orr; besti = oi;
        }
    }

    if (lane == 0) {
        out[(size_t)b * P + p] = (sht > 0) ? (float)bestr : 0.0f;
    }
}

extern "C" void kernel_launch(void* const* d_in, const int* in_sizes, int n_in,
                              void* d_out, int out_size, void* d_ws, size_t ws_size,
                              hipStream_t stream) {
    const float* expr    = (const float*)d_in[0];   // [B, G]
    const float* pathway = (const float*)d_in[1];   // [P, G]
    float* out = (float*)d_out;                     // [B, P]

    const int B = Bc, G = Gc, P = Pc;

    // workspace layout (bytes):
    //   pbits ull[G]          @ 0        (40960 reserved)
    //   runs  ull[B*5120]     @ 40960    (2621440)
    //   wq    f32[B*G]        @ 2662400  (1279744)
    //   mask  ull[B*G]        @ 3942144  (2559488)   total ~6.5 MB
    char* ws = (char*)d_ws;
    ull*   pbits = (ull*)ws;
    ull*   runs  = (ull*)(ws + 40960);
    float* wqa   = (float*)(ws + 2662400);
    ull*   maska = (ull*)(ws + 3942144);

    wave_sort<<<dim3(B * NRUN), dim3(64), 0, stream>>>(expr, pathway, runs, pbits, P, G);
    rank_scatter<<<dim3(NRUN, B), dim3(512), 0, stream>>>(runs, pbits, wqa, maska, G);
    es_kernel<<<dim3((P + 15) / 16, B), dim3(1024), 0, stream>>>(wqa, maska, out, B, P, G);
}

// Round 5
// 121.113 us; speedup vs baseline: 1.3944x; 1.3944x over previous
//
#include <hip/hip_runtime.h>
#include <math.h>

typedef unsigned long long ull;

// Problem constants (from setup_inputs): B=64, G=4999, P=50
constexpr int Bc = 64;
constexpr int Gc = 4999;
constexpr int Pc = 50;

constexpr int RUN  = 1024;           // elements per sorted run
constexpr int NRUN = 5;              // runs per row (5*1024 = 5120 >= G)
constexpr ull PADKEY = 0xFFFFFFFFFFFFFFFFull;
constexpr int LPW = 79;              // ceil(G/64) elements per lane in es

__device__ __forceinline__ ull shfl_xor64(ull v, int lm) {
    int lo = __shfl_xor((int)(unsigned)(v & 0xFFFFFFFFull), lm, 64);
    int hi = __shfl_xor((int)(unsigned)(v >> 32), lm, 64);
    return ((ull)(unsigned)hi << 32) | (unsigned)lo;
}

// ---------------------------------------------------------------------------
// Kernel 1: sort one 1024-element chunk of one row. 256 threads, 4 elems each
// (8 VGPRs for keys — round-4's 16-elem/lane variant spilled to scratch).
// key = (~m)<<32 | idx (unique): ascending u64 == descending value, stable.
// Register stages j<=2, wave-shuffle stages j=4..128, LDS stages j=256,512.
// Blocks with r==0 also pack pathway bits (consumed by next launch — safe).
// ---------------------------------------------------------------------------
__global__ __launch_bounds__(256) void chunk_sort(
    const float* __restrict__ expr, const float* __restrict__ pathway,
    ull* __restrict__ runs, ull* __restrict__ pbits, int P, int G)
{
    __shared__ ull key[RUN];
    const int r = blockIdx.x, b = blockIdx.y, tid = threadIdx.x;
    const int base = tid * 4;
    const float* row = expr + (size_t)b * G;

    ull v[4];
#pragma unroll
    for (int o = 0; o < 4; ++o) {
        int i = r * RUN + base + o;
        if (i < G) {
            unsigned u = __float_as_uint(row[i]);
            unsigned m = (u >> 31) ? ~u : (u | 0x80000000u);  // monotone map
            v[o] = ((ull)(~m) << 32) | (unsigned)i;
        } else {
            v[o] = PADKEY;
        }
    }

    for (int kk = 2; kk <= RUN; kk <<= 1) {
        const int j0 = kk >> 1;
        // LDS stages: j >= 256 (cross-wave)
        if (j0 >= 256) {
#pragma unroll
            for (int o = 0; o < 4; ++o) key[base + o] = v[o];
            __syncthreads();
            for (int j = j0; j >= 256; j >>= 1) {
#pragma unroll
                for (int t = tid; t < RUN / 2; t += 256) {
                    int i  = ((t & ~(j - 1)) << 1) | (t & (j - 1));
                    int ix = i | j;
                    ull a = key[i], c = key[ix];
                    bool up = ((i & kk) == 0);
                    if ((a > c) == up) { key[i] = c; key[ix] = a; }
                }
                __syncthreads();
            }
#pragma unroll
            for (int o = 0; o < 4; ++o) v[o] = key[base + o];
        }
        // wave-shuffle stages: j = min(j0,128) .. 4 (partner tid^(j/4), same wave)
        int jstart = (j0 > 128) ? 128 : j0;
        for (int j = jstart; j >= 4; j >>= 1) {
            int lm = j >> 2;
            bool takeMin = (((tid & lm) == 0) == ((base & kk) == 0));
#pragma unroll
            for (int o = 0; o < 4; ++o) {
                ull c = shfl_xor64(v[o], lm);
                ull mn = (v[o] < c) ? v[o] : c;
                ull mx = (v[o] < c) ? c : v[o];
                v[o] = takeMin ? mn : mx;
            }
        }
        // register stages: j = 2, 1
#pragma unroll
        for (int j = 2; j >= 1; j >>= 1) {
            if (j < kk) {
#pragma unroll
                for (int o = 0; o < 4; ++o) {
                    if ((o & j) == 0) {
                        bool up = (((base + o) & kk) == 0);
                        ull a = v[o], c = v[o | j];
                        if ((a > c) == up) { v[o] = c; v[o | j] = a; }
                    }
                }
            }
        }
    }

    ull* dst = runs + ((size_t)b * NRUN + r) * RUN;
#pragma unroll
    for (int o = 0; o < 4; ++o) dst[base + o] = v[o];

    // Folded pack: blocks with r==0 (64 blocks x 256 thr = 16384 >= G).
    if (r == 0) {
        int g = b * 256 + tid;
        if (g < G) {
            ull m = 0;
            for (int p = 0; p < P; ++p)
                if (pathway[(size_t)p * G + g] > 0.0f) m |= (1ull << p);
            pbits[g] = m;
        }
    }
}

// ---------------------------------------------------------------------------
// Kernel 2: merge-by-rank. Block (r,b): own run's element at position q has
// global rank = q + sum over other 4 runs of countLess(key) (binary search in
// LDS). Unique keys -> bijection onto [0,G). Scatter wq (|v|^0.25 decoded
// from the key) and mask (= pbits[gene], pre-permuted into sorted order).
// 512 threads, 2 elems each: better latency hiding on the search chains.
// ---------------------------------------------------------------------------
__global__ __launch_bounds__(512) void rank_scatter(
    const ull* __restrict__ runs, const ull* __restrict__ pbits,
    float* __restrict__ wqout, ull* __restrict__ maskout, int G)
{
    __shared__ ull other[4][RUN];   // 32 KB
    const int r = blockIdx.x, b = blockIdx.y, tid = threadIdx.x;
    const ull* rowruns = runs + (size_t)b * (NRUN * RUN);

    int k = 0;
    for (int rr = 0; rr < NRUN; ++rr) {
        if (rr == r) continue;
        for (int i = tid; i < RUN; i += 512) other[k][i] = rowruns[rr * RUN + i];
        ++k;
    }
    __syncthreads();

#pragma unroll
    for (int o = 0; o < 2; ++o) {
        const int q = o * 512 + tid;               // own-run rank (coalesced)
        const ull keyv = rowruns[r * RUN + q];
        if (keyv == PADKEY) continue;              // padding sorts to the end
        int rank = q;
#pragma unroll
        for (int kk2 = 0; kk2 < 4; ++kk2) {
            int pos = 0;
#pragma unroll
            for (int s = RUN; s >= 1; s >>= 1) {
                int np = pos + s;
                if (np <= RUN && other[kk2][np - 1] < keyv) pos = np;
            }
            rank += pos;                           // # elements < keyv
        }
        int idx = (int)(unsigned)(keyv & 0xFFFFFFFFu);
        unsigned m = ~((unsigned)(keyv >> 32));
        unsigned absbits = ((m >> 31) ? m : ~m) & 0x7FFFFFFFu;
        float av = __uint_as_float(absbits);
        wqout[(size_t)b * G + rank] = sqrtf(sqrtf(av));   // |v|^0.25
        maskout[(size_t)b * G + rank] = pbits[idx];
    }
}

// ---------------------------------------------------------------------------
// Kernel 3: enrichment scores. Block = 1024 threads (16 waves, 16 pathways)
// per sample b; stages wq + pre-permuted mask into LDS once (coalesced,
// contiguous — no indirection), then each wave scans from LDS.
// ---------------------------------------------------------------------------
__global__ __launch_bounds__(1024) void es_kernel(
    const float* __restrict__ wq, const ull* __restrict__ mask,
    float* __restrict__ out, int B, int P, int G)
{
    __shared__ ull   smask[Gc];   // 39992 B
    __shared__ float swq[Gc];     // 19996 B   (~60 KB total)

    const int tid = threadIdx.x;
    const int b = blockIdx.y;

    for (int i = tid; i < G; i += 1024) {
        swq[i]   = wq[(size_t)b * G + i];
        smask[i] = mask[(size_t)b * G + i];
    }
    __syncthreads();

    const int lane = tid & 63;
    const int w = tid >> 6;
    const int p = blockIdx.x * 16 + w;
    if (p >= P) return;

    const int start = lane * LPW;
    const int end = (start + LPW < G) ? (start + LPW) : G;
    const int cnt = end - start;

    // Pass A: per-chunk (sum w*hit, #hit), butterfly reduce
    double sw = 0.0;
    int sh = 0;
    for (int i = start; i < end; ++i) {
        if ((smask[i] >> p) & 1ull) { sw += (double)swq[i]; sh++; }
    }
    double swt = sw;
    int sht = sh;
#pragma unroll
    for (int off = 1; off < 64; off <<= 1) {
        swt += __shfl_xor(swt, off, 64);
        sht += __shfl_xor(sht, off, 64);
    }
    const double norm      = (swt > 0.0) ? 1.0 / swt : 1.0;
    const double inv_denom = 1.0 / fmax((double)(G - sht), 1.0);

    // Chunk sum (algebraic) + wave inclusive scan -> exclusive prefix
    double csum = sw * norm - (double)(cnt - sh) * inv_denom;
    double x = csum;
#pragma unroll
    for (int off = 1; off < 64; off <<= 1) {
        double vv = __shfl_up(x, off, 64);
        if (lane >= off) x += vv;
    }
    double running = x - csum;

    // Pass C: walk chunk, first-occurrence argmax of |running|
    double bestv = -1.0, bestr = 0.0;
    int besti = 0x7FFFFFFF;
    for (int i = start; i < end; ++i) {
        running += ((smask[i] >> p) & 1ull) ? (double)swq[i] * norm : -inv_denom;
        double a = fabs(running);
        if (a > bestv) { bestv = a; bestr = running; besti = i; }
    }
#pragma unroll
    for (int off = 1; off < 64; off <<= 1) {
        double ov  = __shfl_xor(bestv, off, 64);
        double orr = __shfl_xor(bestr, off, 64);
        int    oi  = __shfl_xor(besti, off, 64);
        if (ov > bestv || (ov == bestv && oi < besti)) {
            bestv = ov; bestr = orr; besti = oi;
        }
    }

    if (lane == 0) {
        out[(size_t)b * P + p] = (sht > 0) ? (float)bestr : 0.0f;
    }
}

extern "C" void kernel_launch(void* const* d_in, const int* in_sizes, int n_in,
                              void* d_out, int out_size, void* d_ws, size_t ws_size,
                              hipStream_t stream) {
    const float* expr    = (const float*)d_in[0];   // [B, G]
    const float* pathway = (const float*)d_in[1];   // [P, G]
    float* out = (float*)d_out;                     // [B, P]

    const int B = Bc, G = Gc, P = Pc;

    // workspace layout (bytes):
    //   pbits ull[G]          @ 0        (40960 reserved)
    //   runs  ull[B*5120]     @ 40960    (2621440)
    //   wq    f32[B*G]        @ 2662400  (1279744)
    //   mask  ull[B*G]        @ 3942144  (2559488)   total ~6.5 MB
    char* ws = (char*)d_ws;
    ull*   pbits = (ull*)ws;
    ull*   runs  = (ull*)(ws + 40960);
    float* wqa   = (float*)(ws + 2662400);
    ull*   maska = (ull*)(ws + 3942144);

    chunk_sort<<<dim3(NRUN, B), dim3(256), 0, stream>>>(expr, pathway, runs, pbits, P, G);
    rank_scatter<<<dim3(NRUN, B), dim3(512), 0, stream>>>(runs, pbits, wqa, maska, G);
    es_kernel<<<dim3((P + 15) / 16, B), dim3(1024), 0, stream>>>(wqa, maska, out, B, P, G);
}